// Round 1
// baseline (588.213 us; speedup 1.0000x reference)
//
#include <hip/hip_runtime.h>

typedef __bf16 bf16;
typedef __attribute__((ext_vector_type(8))) __bf16 bf16x8;
typedef __attribute__((ext_vector_type(4))) __bf16 bf16x4;
typedef __attribute__((ext_vector_type(4))) float f32x4;

#define MFMA16(a, b, c) __builtin_amdgcn_mfma_f32_16x16x32_bf16((a), (b), (c), 0, 0, 0)

__device__ __forceinline__ void gload16(const void* g, void* lds) {
  __builtin_amdgcn_global_load_lds(
      (__attribute__((address_space(1))) unsigned int*)(unsigned long long)g,
      (__attribute__((address_space(3))) unsigned int*)lds, 16, 0, 0);
}

// ---------------- cast X (fp32 -> bf16) ----------------
__global__ void __launch_bounds__(256) cast_x_kernel(const float* __restrict__ X,
                                                     bf16* __restrict__ Xb) {
  int i = (blockIdx.x * 256 + threadIdx.x) * 4;
  f32x4 v = *(const f32x4*)(X + i);
  bf16x4 o;
  o[0] = (bf16)v[0]; o[1] = (bf16)v[1]; o[2] = (bf16)v[2]; o[3] = (bf16)v[3];
  *(bf16x4*)(Xb + i) = o;
}

// ---------------- transpose + cast weight: WT[n][k] = W[k][n] ----------------
__global__ void __launch_bounds__(256) transpose_w_kernel(const float* __restrict__ W,
                                                          bf16* __restrict__ WT) {
  __shared__ float tile[64][65];
  int n0 = (blockIdx.x & 31) * 64;
  int k0 = (blockIdx.x >> 5) * 64;
  int tid = threadIdx.x;
  int r = tid >> 4;
  int c4 = (tid & 15) * 4;
#pragma unroll
  for (int i = 0; i < 4; ++i) {
    f32x4 v = *(const f32x4*)(W + (size_t)(k0 + r + i * 16) * 2048 + n0 + c4);
    tile[r + i * 16][c4 + 0] = v[0];
    tile[r + i * 16][c4 + 1] = v[1];
    tile[r + i * 16][c4 + 2] = v[2];
    tile[r + i * 16][c4 + 3] = v[3];
  }
  __syncthreads();
#pragma unroll
  for (int i = 0; i < 4; ++i) {
    int n = r + i * 16;
    bf16x4 o;
    o[0] = (bf16)tile[c4 + 0][n];
    o[1] = (bf16)tile[c4 + 1][n];
    o[2] = (bf16)tile[c4 + 2][n];
    o[3] = (bf16)tile[c4 + 3][n];
    *(bf16x4*)(WT + (size_t)(n0 + n) * 2048 + k0 + c4) = o;
  }
}

// ---------------- shared 128x128 GEMM core (K=2048, BK=32, 4 waves) ----------------
// A: [M][2048] bf16 row-major (Ag points at row m0). B: [N][2048] bf16 (B^T layout,
// Bg points at row n0). acc[i][j] = 16x16 fragment (wave 2x2 grid of 64x64).
__device__ __forceinline__ void gemm128_core(const bf16* __restrict__ Ag,
                                             const bf16* __restrict__ Bg,
                                             bf16* As, bf16* Bs, f32x4 (&acc)[4][4]) {
  const int K = 2048;
  int tid = threadIdx.x;
  int lane = tid & 63, w = tid >> 6;
  int g = lane >> 4, r16 = lane & 15;
  int wr = w >> 1, wc = w & 1;
  int c0 = tid, c1 = tid + 256;
  const bf16* a0 = Ag + (size_t)(c0 >> 2) * K + (c0 & 3) * 8;
  const bf16* a1 = Ag + (size_t)(c1 >> 2) * K + (c1 & 3) * 8;
  const bf16* b0 = Bg + (size_t)(c0 >> 2) * K + (c0 & 3) * 8;
  const bf16* b1 = Bg + (size_t)(c1 >> 2) * K + (c1 & 3) * 8;
  char* la0 = (char*)As + w * 1024;
  char* la1 = (char*)As + 4096 + w * 1024;
  char* lb0 = (char*)Bs + w * 1024;
  char* lb1 = (char*)Bs + 4096 + w * 1024;

  for (int kt = 0; kt < 64; ++kt) {
    gload16(a0, la0); gload16(a1, la1);
    gload16(b0, lb0); gload16(b1, lb1);
    a0 += 32; a1 += 32; b0 += 32; b1 += 32;
    __syncthreads();
    bf16x8 af[4], bfr[4];
#pragma unroll
    for (int i = 0; i < 4; ++i)
      af[i] = *(const bf16x8*)&As[(wr * 64 + i * 16 + r16) * 32 + g * 8];
#pragma unroll
    for (int j = 0; j < 4; ++j)
      bfr[j] = *(const bf16x8*)&Bs[(wc * 64 + j * 16 + r16) * 32 + g * 8];
#pragma unroll
    for (int i = 0; i < 4; ++i)
#pragma unroll
      for (int j = 0; j < 4; ++j)
        acc[i][j] = MFMA16(af[i], bfr[j], acc[i][j]);
    __syncthreads();
  }
}

// ---------------- QKV projection GEMM, epilogue scatters to tile-major ----------------
// q_t,k_t: [b,h,t][tn=128][hd=64] bf16 (q pre-scaled by 1/8). v_t: [b,h,t][hd=64][tn=128].
__global__ void __launch_bounds__(256) gemm_qkv_kernel(
    const bf16* __restrict__ Xb, const bf16* __restrict__ W0, const bf16* __restrict__ W1,
    const bf16* __restrict__ W2, bf16* __restrict__ q_t, bf16* __restrict__ k_t,
    bf16* __restrict__ v_t) {
  __shared__ bf16 As[128 * 32];
  __shared__ bf16 Bs[128 * 32];
  int bid = blockIdx.x;
  int by = bid / 48, bx = bid % 48;
  int which = bx >> 4;
  int m0 = by * 128, n0 = (bx & 15) * 128;
  const bf16* W = which == 0 ? W0 : (which == 1 ? W1 : W2);

  f32x4 acc[4][4] = {};
  gemm128_core(Xb + (size_t)m0 * 2048, W + (size_t)n0 * 2048, As, Bs, acc);

  int lane = threadIdx.x & 63, w = threadIdx.x >> 6;
  int g = lane >> 4, r16 = lane & 15;
  int wr = w >> 1, wc = w & 1;
#pragma unroll
  for (int i = 0; i < 4; ++i) {
#pragma unroll
    for (int r = 0; r < 4; ++r) {
      int m = m0 + wr * 64 + i * 16 + g * 4 + r;
      int b = m >> 12, s = m & 4095;
      int hg = s >> 6, wg = s & 63;
      int t = ((hg >> 3) << 2) + (wg >> 4);
      int tn = ((hg & 7) << 4) + (wg & 15);
#pragma unroll
      for (int j = 0; j < 4; ++j) {
        int n = n0 + wc * 64 + j * 16 + r16;
        int h = n >> 6, hd = n & 63;
        float val = acc[i][j][r];
        size_t base = ((size_t)(b * 32 + h) * 32 + t);
        if (which == 0)
          q_t[(base * 128 + tn) * 64 + hd] = (bf16)(val * 0.125f);
        else if (which == 1)
          k_t[(base * 128 + tn) * 64 + hd] = (bf16)val;
        else
          v_t[(base * 64 + hd) * 128 + tn] = (bf16)val;
      }
    }
  }
}

// ---------------- output GEMM: out = o_bf @ Wo, fp32 row-major ----------------
__global__ void __launch_bounds__(256) gemm_out_kernel(const bf16* __restrict__ A,
                                                       const bf16* __restrict__ W,
                                                       float* __restrict__ C) {
  __shared__ bf16 As[128 * 32];
  __shared__ bf16 Bs[128 * 32];
  int bid = blockIdx.x;
  int by = bid >> 4, bx = bid & 15;
  int m0 = by * 128, n0 = bx * 128;

  f32x4 acc[4][4] = {};
  gemm128_core(A + (size_t)m0 * 2048, W + (size_t)n0 * 2048, As, Bs, acc);

  int lane = threadIdx.x & 63, w = threadIdx.x >> 6;
  int g = lane >> 4, r16 = lane & 15;
  int wr = w >> 1, wc = w & 1;
#pragma unroll
  for (int i = 0; i < 4; ++i)
#pragma unroll
    for (int j = 0; j < 4; ++j)
#pragma unroll
      for (int r = 0; r < 4; ++r) {
        int m = m0 + wr * 64 + i * 16 + g * 4 + r;
        int n = n0 + wc * 64 + j * 16 + r16;
        C[(size_t)m * 2048 + n] = acc[i][j][r];
      }
}

// ---------------- block-sparse tile attention ----------------
// grid = (b*32+h)*32+t; 4 waves, wave w owns q rows [w*32, w*32+32).
__global__ void __launch_bounds__(256) attn_kernel(const bf16* __restrict__ q_t,
                                                   const bf16* __restrict__ k_t,
                                                   const bf16* __restrict__ v_t,
                                                   bf16* __restrict__ o_bf) {
  __shared__ char Pl[128 * 256];  // P tile, bf16, XOR-swizzled rows of 256B
  int bid = blockIdx.x;
  int t = bid & 31, bh = bid >> 5;
  int h = bh & 31, b = bh >> 5;
  int tid = threadIdx.x, w = tid >> 6, lane = tid & 63;
  int g = lane >> 4, r16 = lane & 15;

  const size_t qoff = (size_t)bid * (128 * 64);
  bf16x8 qf[2][2];
#pragma unroll
  for (int mf = 0; mf < 2; ++mf)
#pragma unroll
    for (int kf = 0; kf < 2; ++kf)
      qf[mf][kf] = *(const bf16x8*)&q_t[qoff + (size_t)(w * 32 + mf * 16 + r16) * 64 + kf * 32 + g * 8];

  f32x4 oacc[2][4] = {};
  float mrun[2][4], lrun[2][4];
#pragma unroll
  for (int mf = 0; mf < 2; ++mf)
#pragma unroll
    for (int r = 0; r < 4; ++r) { mrun[mf][r] = -1e30f; lrun[mf][r] = 0.f; }

  int qh = t >> 2, qw = t & 3;
  int ch = qh < 1 ? 1 : (qh > 7 ? 7 : qh);
  int cw = qw < 1 ? 1 : (qw > 3 ? 3 : qw);

  for (int c = 0; c < 4; ++c) {
    int vt = (ch - 1 + (c >> 1)) * 4 + (cw - 1 + (c & 1));
    const bf16* Kt = k_t + ((size_t)bh * 32 + vt) * (128 * 64);
    const bf16* Vt = v_t + ((size_t)bh * 32 + vt) * (128 * 64);

    // S = (Q*SCALE) K^T  for this kv tile: s[mf][nf] = 16x16 frag
    f32x4 s[2][8];
#pragma unroll
    for (int nf = 0; nf < 8; ++nf) {
      bf16x8 kf0 = *(const bf16x8*)&Kt[(nf * 16 + r16) * 64 + g * 8];
      bf16x8 kf1 = *(const bf16x8*)&Kt[(nf * 16 + r16) * 64 + 32 + g * 8];
#pragma unroll
      for (int mf = 0; mf < 2; ++mf) {
        f32x4 z = {};
        z = MFMA16(qf[mf][0], kf0, z);
        z = MFMA16(qf[mf][1], kf1, z);
        s[mf][nf] = z;
      }
    }

    // online softmax update (rows owned per lane-group: row = g*4+r)
#pragma unroll
    for (int mf = 0; mf < 2; ++mf) {
#pragma unroll
      for (int r = 0; r < 4; ++r) {
        float mx = s[mf][0][r];
#pragma unroll
        for (int nf = 1; nf < 8; ++nf) mx = fmaxf(mx, s[mf][nf][r]);
        mx = fmaxf(mx, __shfl_xor(mx, 1));
        mx = fmaxf(mx, __shfl_xor(mx, 2));
        mx = fmaxf(mx, __shfl_xor(mx, 4));
        mx = fmaxf(mx, __shfl_xor(mx, 8));
        float mold = mrun[mf][r];
        float mnew = fmaxf(mold, mx);
        float sc = __expf(mold - mnew);
        mrun[mf][r] = mnew;
        float ps = 0.f;
#pragma unroll
        for (int nf = 0; nf < 8; ++nf) {
          float p = __expf(s[mf][nf][r] - mnew);
          s[mf][nf][r] = p;
          ps += p;
        }
        ps += __shfl_xor(ps, 1);
        ps += __shfl_xor(ps, 2);
        ps += __shfl_xor(ps, 4);
        ps += __shfl_xor(ps, 8);
        lrun[mf][r] = lrun[mf][r] * sc + ps;
#pragma unroll
        for (int hf = 0; hf < 4; ++hf) oacc[mf][hf][r] *= sc;
      }
    }

    // store P (bf16) to swizzled LDS slab (wave-private rows)
#pragma unroll
    for (int mf = 0; mf < 2; ++mf)
#pragma unroll
      for (int r = 0; r < 4; ++r) {
        int row = w * 32 + mf * 16 + g * 4 + r;
        int rb = row * 256;
        int swz = (row & 7) << 4;
#pragma unroll
        for (int nf = 0; nf < 8; ++nf) {
          int addr = (rb + (nf * 16 + r16) * 2) ^ swz;
          *(bf16*)(Pl + addr) = (bf16)s[mf][nf][r];
        }
      }
    __syncthreads();

    // O += P @ V   (V^T layout: Vt[hd][tn])
#pragma unroll
    for (int ks = 0; ks < 4; ++ks) {
      bf16x8 pf[2];
#pragma unroll
      for (int mf = 0; mf < 2; ++mf) {
        int row = w * 32 + mf * 16 + r16;
        int addr = (row * 256 + ks * 64 + g * 16) ^ ((row & 7) << 4);
        pf[mf] = *(const bf16x8*)(Pl + addr);
      }
      bf16x8 vf[4];
#pragma unroll
      for (int hf = 0; hf < 4; ++hf)
        vf[hf] = *(const bf16x8*)&Vt[(hf * 16 + r16) * 128 + ks * 32 + g * 8];
#pragma unroll
      for (int mf = 0; mf < 2; ++mf)
#pragma unroll
        for (int hf = 0; hf < 4; ++hf)
          oacc[mf][hf] = MFMA16(pf[mf], vf[hf], oacc[mf][hf]);
    }
    __syncthreads();
  }

  // epilogue: normalize and write de-tiled bf16 [b, s, h*64+hd]
  int nth = t >> 2, ntw = t & 3;
#pragma unroll
  for (int mf = 0; mf < 2; ++mf)
#pragma unroll
    for (int r = 0; r < 4; ++r) {
      float inv = __builtin_amdgcn_rcpf(lrun[mf][r]);
      int tn = w * 32 + mf * 16 + g * 4 + r;
      int stok = (nth * 8 + (tn >> 4)) * 64 + ntw * 16 + (tn & 15);
#pragma unroll
      for (int hf = 0; hf < 4; ++hf) {
        int col = h * 64 + hf * 16 + r16;
        o_bf[((size_t)b * 4096 + stok) * 2048 + col] = (bf16)(oacc[mf][hf][r] * inv);
      }
    }
}

// ---------------- launcher ----------------
extern "C" void kernel_launch(void* const* d_in, const int* in_sizes, int n_in,
                              void* d_out, int out_size, void* d_ws, size_t ws_size,
                              hipStream_t stream) {
  const float* X = (const float*)d_in[0];
  const float* Wq = (const float*)d_in[1];
  const float* Wk = (const float*)d_in[2];
  const float* Wv = (const float*)d_in[3];
  const float* Wo = (const float*)d_in[4];
  float* out = (float*)d_out;
  char* ws = (char*)d_ws;
  if (ws_size < 159383552u) return;  // need ~159.4 MB scratch

  bf16* Xb  = (bf16*)(ws + 0);           // 33.5 MB, later reused as o_bf
  bf16* WT0 = (bf16*)(ws + 33554432u);   // 8.4 MB (WqT, later WoT)
  bf16* WT1 = (bf16*)(ws + 41943040u);   // WkT
  bf16* WT2 = (bf16*)(ws + 50331648u);   // WvT
  bf16* q_t = (bf16*)(ws + 58720256u);   // 33.5 MB
  bf16* k_t = (bf16*)(ws + 92274688u);   // 33.5 MB
  bf16* v_t = (bf16*)(ws + 125829120u);  // 33.5 MB
  bf16* o_bf = Xb;

  cast_x_kernel<<<16384, 256, 0, stream>>>(X, Xb);
  transpose_w_kernel<<<1024, 256, 0, stream>>>(Wq, WT0);
  transpose_w_kernel<<<1024, 256, 0, stream>>>(Wk, WT1);
  transpose_w_kernel<<<1024, 256, 0, stream>>>(Wv, WT2);
  gemm_qkv_kernel<<<3072, 256, 0, stream>>>(Xb, WT0, WT1, WT2, q_t, k_t, v_t);
  attn_kernel<<<2048, 256, 0, stream>>>(q_t, k_t, v_t, o_bf);
  transpose_w_kernel<<<1024, 256, 0, stream>>>(Wo, WT0);
  gemm_out_kernel<<<1024, 256, 0, stream>>>(o_bf, WT0, out);
}

// Round 2
// 519.130 us; speedup vs baseline: 1.1331x; 1.1331x over previous
//
#include <hip/hip_runtime.h>

typedef __bf16 bf16;
typedef __attribute__((ext_vector_type(8))) __bf16 bf16x8;
typedef __attribute__((ext_vector_type(4))) __bf16 bf16x4;
typedef __attribute__((ext_vector_type(4))) float f32x4;

#define MFMA16(a, b, c) __builtin_amdgcn_mfma_f32_16x16x32_bf16((a), (b), (c), 0, 0, 0)

__device__ __forceinline__ void gload16(const void* g, void* lds) {
  __builtin_amdgcn_global_load_lds(
      (__attribute__((address_space(1))) unsigned int*)(unsigned long long)g,
      (__attribute__((address_space(3))) unsigned int*)lds, 16, 0, 0);
}

// ---------------- cast X (fp32 -> bf16) ----------------
__global__ void __launch_bounds__(256) cast_x_kernel(const float* __restrict__ X,
                                                     bf16* __restrict__ Xb) {
  int i = (blockIdx.x * 256 + threadIdx.x) * 4;
  f32x4 v = *(const f32x4*)(X + i);
  bf16x4 o;
  o[0] = (bf16)v[0]; o[1] = (bf16)v[1]; o[2] = (bf16)v[2]; o[3] = (bf16)v[3];
  *(bf16x4*)(Xb + i) = o;
}

// ---------------- transpose + cast weight: WT[n][k] = W[k][n] ----------------
__global__ void __launch_bounds__(256) transpose_w_kernel(const float* __restrict__ W,
                                                          bf16* __restrict__ WT) {
  __shared__ float tile[64][65];
  int n0 = (blockIdx.x & 31) * 64;
  int k0 = (blockIdx.x >> 5) * 64;
  int tid = threadIdx.x;
  int r = tid >> 4;
  int c4 = (tid & 15) * 4;
#pragma unroll
  for (int i = 0; i < 4; ++i) {
    f32x4 v = *(const f32x4*)(W + (size_t)(k0 + r + i * 16) * 2048 + n0 + c4);
    tile[r + i * 16][c4 + 0] = v[0];
    tile[r + i * 16][c4 + 1] = v[1];
    tile[r + i * 16][c4 + 2] = v[2];
    tile[r + i * 16][c4 + 3] = v[3];
  }
  __syncthreads();
#pragma unroll
  for (int i = 0; i < 4; ++i) {
    int n = r + i * 16;
    bf16x4 o;
    o[0] = (bf16)tile[c4 + 0][n];
    o[1] = (bf16)tile[c4 + 1][n];
    o[2] = (bf16)tile[c4 + 2][n];
    o[3] = (bf16)tile[c4 + 3][n];
    *(bf16x4*)(WT + (size_t)(n0 + n) * 2048 + k0 + c4) = o;
  }
}

// ---------------- 256x256 deep-pipelined GEMM core (K=2048, BK=32) ----------------
// 8 waves (2M x 4N), per-wave C block 128x64. LDS: 3-buffer ring, 32KB/buf
// (A 16KB [256][32] + B 16KB [256][32], both XOR-swizzled). Depth-2 prefetch,
// counted vmcnt(4) once per K-tile, setprio around MFMA clusters.
// A: [M][2048] bf16 row-major (Ag at row m0). B: [N][2048] bf16 (Bg at row n0).
__device__ __forceinline__ void gemm256_core(const bf16* __restrict__ Ag,
                                             const bf16* __restrict__ Bg,
                                             char* lds, f32x4 (&acc)[8][4]) {
  const int tid = threadIdx.x;
  const int lane = tid & 63, wid = tid >> 6;
  const int g = lane >> 4, r16 = lane & 15;
  const int wm = wid >> 2, wn = wid & 3;
  // read-side swizzle: byte = row*64 + ((g ^ ((row>>1)&3))<<4); (row>>1)&3 == (r16>>1)&3
  const int swz = ((g ^ ((r16 >> 1) & 3)) << 4);

  // staging: per wave 2 loads/half (A,B): rows wid*32 + i*16 + (lane>>2),
  // source col group pre-swizzled so linear LDS dest + swizzled read match.
  const int srow = wid * 32 + (lane >> 2);
  const int scol = ((lane & 3) ^ ((lane >> 3) & 3)) * 8;  // bf16 elems
  const bf16* gA = Ag + (size_t)srow * 2048 + scol;
  const bf16* gB = Bg + (size_t)srow * 2048 + scol;
  char* sA = lds + wid * 2048;           // + buf*32768 (+1024 for 2nd load)
  char* sB = lds + 16384 + wid * 2048;

  const int arow0 = wm * 128 + r16;  // + i*16
  const int brow0 = wn * 64 + r16;   // + j*16

#define STAGE_A(bf_, tt_)                              \
  {                                                    \
    char* d_ = sA + (bf_) * 32768;                     \
    const bf16* s_ = gA + (size_t)(tt_) * 32;          \
    gload16(s_, d_);                                   \
    gload16(s_ + (size_t)16 * 2048, d_ + 1024);        \
  }
#define STAGE_B(bf_, tt_)                              \
  {                                                    \
    char* d_ = sB + (bf_) * 32768;                     \
    const bf16* s_ = gB + (size_t)(tt_) * 32;          \
    gload16(s_, d_);                                   \
    gload16(s_ + (size_t)16 * 2048, d_ + 1024);        \
  }

  // prologue: stage tiles 0 and 1; wait for tile 0 (leave tile 1 in flight)
  STAGE_A(0, 0) STAGE_B(0, 0) STAGE_A(1, 1) STAGE_B(1, 1)
  asm volatile("s_waitcnt vmcnt(4)" ::: "memory");
  __builtin_amdgcn_s_barrier();

  int c = 0;
  for (int t = 0; t < 64; ++t) {
    const char* Ab = lds + c * 32768;
    const char* Bb = Ab + 16384;
    int sbuf = c + 2; if (sbuf >= 3) sbuf -= 3;
    const bool stage = (t < 62);

    // ---- phase 0: B frags + A frags (i 0..3), stage next A, MFMA quadrant 0 ----
    bf16x8 bfr[4], af[4];
#pragma unroll
    for (int j = 0; j < 4; ++j)
      bfr[j] = *(const bf16x8*)(Bb + (brow0 + j * 16) * 64 + swz);
#pragma unroll
    for (int i = 0; i < 4; ++i)
      af[i] = *(const bf16x8*)(Ab + (arow0 + i * 16) * 64 + swz);
    if (stage) STAGE_A(sbuf, t + 2)
    __builtin_amdgcn_s_barrier();
    __builtin_amdgcn_sched_barrier(0);
    __builtin_amdgcn_s_setprio(1);
#pragma unroll
    for (int i = 0; i < 4; ++i)
#pragma unroll
      for (int j = 0; j < 4; ++j)
        acc[i][j] = MFMA16(af[i], bfr[j], acc[i][j]);
    __builtin_amdgcn_s_setprio(0);
    __builtin_amdgcn_s_barrier();

    // ---- phase 1: A frags (i 4..7), stage next B, counted wait, MFMA quadrant 1 ----
#pragma unroll
    for (int i = 0; i < 4; ++i)
      af[i] = *(const bf16x8*)(Ab + (arow0 + (i + 4) * 16) * 64 + swz);
    if (stage) STAGE_B(sbuf, t + 2)
    if (t < 62) {
      asm volatile("s_waitcnt vmcnt(4)" ::: "memory");  // tile t+1 resident; t+2 in flight
    } else if (t == 62) {
      asm volatile("s_waitcnt vmcnt(0)" ::: "memory");  // epilogue drain
    }
    __builtin_amdgcn_s_barrier();
    __builtin_amdgcn_sched_barrier(0);
    __builtin_amdgcn_s_setprio(1);
#pragma unroll
    for (int i = 0; i < 4; ++i)
#pragma unroll
      for (int j = 0; j < 4; ++j)
        acc[i + 4][j] = MFMA16(af[i], bfr[j], acc[i + 4][j]);
    __builtin_amdgcn_s_setprio(0);
    __builtin_amdgcn_s_barrier();

    c += 1; if (c >= 3) c -= 3;
  }
#undef STAGE_A
#undef STAGE_B
}

// ---------------- QKV projection GEMM (256^2 tile), scatter to tile-major ----------------
__global__ void __launch_bounds__(512, 2) gemm_qkv_kernel(
    const bf16* __restrict__ Xb, const bf16* __restrict__ W0, const bf16* __restrict__ W1,
    const bf16* __restrict__ W2, bf16* __restrict__ q_t, bf16* __restrict__ k_t,
    bf16* __restrict__ v_t) {
  __shared__ char lds[98304];
  int bid = blockIdx.x;
  int xcd = bid & 7, idx = bid >> 3;          // 768 = 8 XCD chunks of 96
  int by = xcd * 4 + idx / 24, bx = idx % 24; // m-major within chunk for L2 reuse
  int which = bx >> 3;
  int m0 = by * 256, n0 = (bx & 7) * 256;
  const bf16* W = which == 0 ? W0 : (which == 1 ? W1 : W2);

  f32x4 acc[8][4] = {};
  gemm256_core(Xb + (size_t)m0 * 2048, W + (size_t)n0 * 2048, lds, acc);

  int lane = threadIdx.x & 63, wid = threadIdx.x >> 6;
  int g = lane >> 4, r16 = lane & 15;
  int wm = wid >> 2, wn = wid & 3;
#pragma unroll
  for (int i = 0; i < 8; ++i) {
#pragma unroll
    for (int r = 0; r < 4; ++r) {
      int m = m0 + wm * 128 + i * 16 + g * 4 + r;
      int b = m >> 12, s = m & 4095;
      int hg = s >> 6, wg = s & 63;
      int t = ((hg >> 3) << 2) + (wg >> 4);
      int tn = ((hg & 7) << 4) + (wg & 15);
#pragma unroll
      for (int j = 0; j < 4; ++j) {
        int n = n0 + wn * 64 + j * 16 + r16;
        int h = n >> 6, hd = n & 63;
        float val = acc[i][j][r];
        size_t base = ((size_t)(b * 32 + h) * 32 + t);
        if (which == 0)
          q_t[(base * 128 + tn) * 64 + hd] = (bf16)(val * 0.125f);
        else if (which == 1)
          k_t[(base * 128 + tn) * 64 + hd] = (bf16)val;
        else
          v_t[(base * 64 + hd) * 128 + tn] = (bf16)val;
      }
    }
  }
}

// ---------------- output GEMM: out = o_bf @ Wo, fp32 row-major ----------------
__global__ void __launch_bounds__(512, 2) gemm_out_kernel(const bf16* __restrict__ A,
                                                          const bf16* __restrict__ W,
                                                          float* __restrict__ C) {
  __shared__ char lds[98304];
  int bid = blockIdx.x;
  int xcd = bid & 7, idx = bid >> 3;         // 256 = 8 chunks of 32
  int by = xcd * 4 + idx / 8, bx = idx & 7;
  int m0 = by * 256, n0 = bx * 256;

  f32x4 acc[8][4] = {};
  gemm256_core(A + (size_t)m0 * 2048, W + (size_t)n0 * 2048, lds, acc);

  int lane = threadIdx.x & 63, wid = threadIdx.x >> 6;
  int g = lane >> 4, r16 = lane & 15;
  int wm = wid >> 2, wn = wid & 3;
#pragma unroll
  for (int i = 0; i < 8; ++i)
#pragma unroll
    for (int j = 0; j < 4; ++j)
#pragma unroll
      for (int r = 0; r < 4; ++r) {
        int m = m0 + wm * 128 + i * 16 + g * 4 + r;
        int n = n0 + wn * 64 + j * 16 + r16;
        C[(size_t)m * 2048 + n] = acc[i][j][r];
      }
}

// ---------------- block-sparse tile attention (unchanged, passing) ----------------
__global__ void __launch_bounds__(256) attn_kernel(const bf16* __restrict__ q_t,
                                                   const bf16* __restrict__ k_t,
                                                   const bf16* __restrict__ v_t,
                                                   bf16* __restrict__ o_bf) {
  __shared__ char Pl[128 * 256];  // P tile, bf16, XOR-swizzled rows of 256B
  int bid = blockIdx.x;
  int t = bid & 31, bh = bid >> 5;
  int h = bh & 31, b = bh >> 5;
  int tid = threadIdx.x, w = tid >> 6, lane = tid & 63;
  int g = lane >> 4, r16 = lane & 15;

  const size_t qoff = (size_t)bid * (128 * 64);
  bf16x8 qf[2][2];
#pragma unroll
  for (int mf = 0; mf < 2; ++mf)
#pragma unroll
    for (int kf = 0; kf < 2; ++kf)
      qf[mf][kf] = *(const bf16x8*)&q_t[qoff + (size_t)(w * 32 + mf * 16 + r16) * 64 + kf * 32 + g * 8];

  f32x4 oacc[2][4] = {};
  float mrun[2][4], lrun[2][4];
#pragma unroll
  for (int mf = 0; mf < 2; ++mf)
#pragma unroll
    for (int r = 0; r < 4; ++r) { mrun[mf][r] = -1e30f; lrun[mf][r] = 0.f; }

  int qh = t >> 2, qw = t & 3;
  int ch = qh < 1 ? 1 : (qh > 7 ? 7 : qh);
  int cw = qw < 1 ? 1 : (qw > 3 ? 3 : qw);

  for (int c = 0; c < 4; ++c) {
    int vt = (ch - 1 + (c >> 1)) * 4 + (cw - 1 + (c & 1));
    const bf16* Kt = k_t + ((size_t)bh * 32 + vt) * (128 * 64);
    const bf16* Vt = v_t + ((size_t)bh * 32 + vt) * (128 * 64);

    f32x4 s[2][8];
#pragma unroll
    for (int nf = 0; nf < 8; ++nf) {
      bf16x8 kf0 = *(const bf16x8*)&Kt[(nf * 16 + r16) * 64 + g * 8];
      bf16x8 kf1 = *(const bf16x8*)&Kt[(nf * 16 + r16) * 64 + 32 + g * 8];
#pragma unroll
      for (int mf = 0; mf < 2; ++mf) {
        f32x4 z = {};
        z = MFMA16(qf[mf][0], kf0, z);
        z = MFMA16(qf[mf][1], kf1, z);
        s[mf][nf] = z;
      }
    }

#pragma unroll
    for (int mf = 0; mf < 2; ++mf) {
#pragma unroll
      for (int r = 0; r < 4; ++r) {
        float mx = s[mf][0][r];
#pragma unroll
        for (int nf = 1; nf < 8; ++nf) mx = fmaxf(mx, s[mf][nf][r]);
        mx = fmaxf(mx, __shfl_xor(mx, 1));
        mx = fmaxf(mx, __shfl_xor(mx, 2));
        mx = fmaxf(mx, __shfl_xor(mx, 4));
        mx = fmaxf(mx, __shfl_xor(mx, 8));
        float mold = mrun[mf][r];
        float mnew = fmaxf(mold, mx);
        float sc = __expf(mold - mnew);
        mrun[mf][r] = mnew;
        float ps = 0.f;
#pragma unroll
        for (int nf = 0; nf < 8; ++nf) {
          float p = __expf(s[mf][nf][r] - mnew);
          s[mf][nf][r] = p;
          ps += p;
        }
        ps += __shfl_xor(ps, 1);
        ps += __shfl_xor(ps, 2);
        ps += __shfl_xor(ps, 4);
        ps += __shfl_xor(ps, 8);
        lrun[mf][r] = lrun[mf][r] * sc + ps;
#pragma unroll
        for (int hf = 0; hf < 4; ++hf) oacc[mf][hf][r] *= sc;
      }
    }

#pragma unroll
    for (int mf = 0; mf < 2; ++mf)
#pragma unroll
      for (int r = 0; r < 4; ++r) {
        int row = w * 32 + mf * 16 + g * 4 + r;
        int rb = row * 256;
        int swzp = (row & 7) << 4;
#pragma unroll
        for (int nf = 0; nf < 8; ++nf) {
          int addr = (rb + (nf * 16 + r16) * 2) ^ swzp;
          *(bf16*)(Pl + addr) = (bf16)s[mf][nf][r];
        }
      }
    __syncthreads();

#pragma unroll
    for (int ks = 0; ks < 4; ++ks) {
      bf16x8 pf[2];
#pragma unroll
      for (int mf = 0; mf < 2; ++mf) {
        int row = w * 32 + mf * 16 + r16;
        int addr = (row * 256 + ks * 64 + g * 16) ^ ((row & 7) << 4);
        pf[mf] = *(const bf16x8*)(Pl + addr);
      }
      bf16x8 vf[4];
#pragma unroll
      for (int hf = 0; hf < 4; ++hf)
        vf[hf] = *(const bf16x8*)&Vt[(hf * 16 + r16) * 128 + ks * 32 + g * 8];
#pragma unroll
      for (int mf = 0; mf < 2; ++mf)
#pragma unroll
        for (int hf = 0; hf < 4; ++hf)
          oacc[mf][hf] = MFMA16(pf[mf], vf[hf], oacc[mf][hf]);
    }
    __syncthreads();
  }

  int nth = t >> 2, ntw = t & 3;
#pragma unroll
  for (int mf = 0; mf < 2; ++mf)
#pragma unroll
    for (int r = 0; r < 4; ++r) {
      float inv = __builtin_amdgcn_rcpf(lrun[mf][r]);
      int tn = w * 32 + mf * 16 + g * 4 + r;
      int stok = (nth * 8 + (tn >> 4)) * 64 + ntw * 16 + (tn & 15);
#pragma unroll
      for (int hf = 0; hf < 4; ++hf) {
        int col = h * 64 + hf * 16 + r16;
        o_bf[((size_t)b * 4096 + stok) * 2048 + col] = (bf16)(oacc[mf][hf][r] * inv);
      }
    }
}

// ---------------- launcher ----------------
extern "C" void kernel_launch(void* const* d_in, const int* in_sizes, int n_in,
                              void* d_out, int out_size, void* d_ws, size_t ws_size,
                              hipStream_t stream) {
  const float* X = (const float*)d_in[0];
  const float* Wq = (const float*)d_in[1];
  const float* Wk = (const float*)d_in[2];
  const float* Wv = (const float*)d_in[3];
  const float* Wo = (const float*)d_in[4];
  float* out = (float*)d_out;
  char* ws = (char*)d_ws;
  if (ws_size < 159383552u) return;  // need ~159.4 MB scratch

  bf16* Xb  = (bf16*)(ws + 0);           // 33.5 MB, later reused as o_bf
  bf16* WT0 = (bf16*)(ws + 33554432u);   // 8.4 MB (WqT, later WoT)
  bf16* WT1 = (bf16*)(ws + 41943040u);   // WkT
  bf16* WT2 = (bf16*)(ws + 50331648u);   // WvT
  bf16* q_t = (bf16*)(ws + 58720256u);   // 33.5 MB
  bf16* k_t = (bf16*)(ws + 92274688u);   // 33.5 MB
  bf16* v_t = (bf16*)(ws + 125829120u);  // 33.5 MB
  bf16* o_bf = Xb;

  cast_x_kernel<<<16384, 256, 0, stream>>>(X, Xb);
  transpose_w_kernel<<<1024, 256, 0, stream>>>(Wq, WT0);
  transpose_w_kernel<<<1024, 256, 0, stream>>>(Wk, WT1);
  transpose_w_kernel<<<1024, 256, 0, stream>>>(Wv, WT2);
  gemm_qkv_kernel<<<768, 512, 0, stream>>>(Xb, WT0, WT1, WT2, q_t, k_t, v_t);
  attn_kernel<<<2048, 256, 0, stream>>>(q_t, k_t, v_t, o_bf);
  transpose_w_kernel<<<1024, 256, 0, stream>>>(Wo, WT0);
  gemm_out_kernel<<<256, 512, 0, stream>>>(o_bf, WT0, out);
}

// Round 3
// 510.163 us; speedup vs baseline: 1.1530x; 1.0176x over previous
//
#include <hip/hip_runtime.h>

typedef __bf16 bf16;
typedef __attribute__((ext_vector_type(8))) __bf16 bf16x8;
typedef __attribute__((ext_vector_type(4))) __bf16 bf16x4;
typedef __attribute__((ext_vector_type(4))) float f32x4;

#define MFMA16(a, b, c) __builtin_amdgcn_mfma_f32_16x16x32_bf16((a), (b), (c), 0, 0, 0)

__device__ __forceinline__ void gload16(const void* g, void* lds) {
  __builtin_amdgcn_global_load_lds(
      (__attribute__((address_space(1))) unsigned int*)(unsigned long long)g,
      (__attribute__((address_space(3))) unsigned int*)lds, 16, 0, 0);
}

// ---------------- cast X (fp32 -> bf16) ----------------
__global__ void __launch_bounds__(256) cast_x_kernel(const float* __restrict__ X,
                                                     bf16* __restrict__ Xb) {
  int i = (blockIdx.x * 256 + threadIdx.x) * 4;
  f32x4 v = *(const f32x4*)(X + i);
  bf16x4 o;
  o[0] = (bf16)v[0]; o[1] = (bf16)v[1]; o[2] = (bf16)v[2]; o[3] = (bf16)v[3];
  *(bf16x4*)(Xb + i) = o;
}

// ---------------- transpose + cast weight: WT[n][k] = W[k][n] ----------------
__global__ void __launch_bounds__(256) transpose_w_kernel(const float* __restrict__ W,
                                                          bf16* __restrict__ WT) {
  __shared__ float tile[64][65];
  int n0 = (blockIdx.x & 31) * 64;
  int k0 = (blockIdx.x >> 5) * 64;
  int tid = threadIdx.x;
  int r = tid >> 4;
  int c4 = (tid & 15) * 4;
#pragma unroll
  for (int i = 0; i < 4; ++i) {
    f32x4 v = *(const f32x4*)(W + (size_t)(k0 + r + i * 16) * 2048 + n0 + c4);
    tile[r + i * 16][c4 + 0] = v[0];
    tile[r + i * 16][c4 + 1] = v[1];
    tile[r + i * 16][c4 + 2] = v[2];
    tile[r + i * 16][c4 + 3] = v[3];
  }
  __syncthreads();
#pragma unroll
  for (int i = 0; i < 4; ++i) {
    int n = r + i * 16;
    bf16x4 o;
    o[0] = (bf16)tile[c4 + 0][n];
    o[1] = (bf16)tile[c4 + 1][n];
    o[2] = (bf16)tile[c4 + 2][n];
    o[3] = (bf16)tile[c4 + 3][n];
    *(bf16x4*)(WT + (size_t)(n0 + n) * 2048 + k0 + c4) = o;
  }
}

// ---------------- 256x256 GEMM core, 1-barrier/iter ring-3 pipeline ----------------
// 8 waves (2M x 4N), per-wave C block 128x64. LDS: 3-buffer ring, 32KB/buf
// (A 16KB [256][32] + B 16KB [256][32], XOR-swizzled). Stage depth 2 (tile t+2),
// counted vmcnt(4), ONE s_barrier per K-iter: ds_reads and MFMAs free to
// interleave within the iter (compiler fine-grained lgkmcnt), LDS drain
// overlaps MFMA via wave stagger.
__device__ __forceinline__ void gemm256_core(const bf16* __restrict__ Ag,
                                             const bf16* __restrict__ Bg,
                                             char* lds, f32x4 (&acc)[8][4]) {
  const int tid = threadIdx.x;
  const int lane = tid & 63, wid = tid >> 6;
  const int g = lane >> 4, r16 = lane & 15;
  const int wm = wid >> 2, wn = wid & 3;
  // read-side swizzle: byte = row*64 + ((g ^ ((row>>1)&3))<<4)
  const int swz = ((g ^ ((r16 >> 1) & 3)) << 4);

  const int srow = wid * 32 + (lane >> 2);
  const int scol = ((lane & 3) ^ ((lane >> 3) & 3)) * 8;  // pre-swizzled source col
  const bf16* gA = Ag + (size_t)srow * 2048 + scol;
  const bf16* gB = Bg + (size_t)srow * 2048 + scol;
  char* sA = lds + wid * 2048;           // + buf*32768 (+1024 for 2nd 16 rows)
  char* sB = lds + 16384 + wid * 2048;

  const int arow0 = wm * 128 + r16;  // + i*16
  const int brow0 = wn * 64 + r16;   // + j*16

#define STAGE_A(bf_, tt_)                              \
  {                                                    \
    char* d_ = sA + (bf_) * 32768;                     \
    const bf16* s_ = gA + (size_t)(tt_) * 32;          \
    gload16(s_, d_);                                   \
    gload16(s_ + (size_t)16 * 2048, d_ + 1024);        \
  }
#define STAGE_B(bf_, tt_)                              \
  {                                                    \
    char* d_ = sB + (bf_) * 32768;                     \
    const bf16* s_ = gB + (size_t)(tt_) * 32;          \
    gload16(s_, d_);                                   \
    gload16(s_ + (size_t)16 * 2048, d_ + 1024);        \
  }

  // prologue: stage tiles 0 and 1; wait for tile 0 (leave tile 1 in flight)
  STAGE_A(0, 0) STAGE_B(0, 0) STAGE_A(1, 1) STAGE_B(1, 1)
  asm volatile("s_waitcnt vmcnt(4)" ::: "memory");
  __builtin_amdgcn_s_barrier();
  __builtin_amdgcn_sched_barrier(0);

  int c = 0;
  for (int t = 0; t < 64; ++t) {
    const char* Ab = lds + c * 32768;
    const char* Bb = Ab + 16384;
    int sbuf = c + 2; if (sbuf >= 3) sbuf -= 3;

    // ds_reads first (before any LDS clobber this iter) — compiler interleaves
    // these with the MFMAs below via fine-grained lgkmcnt.
    bf16x8 bfr[4], af[8];
#pragma unroll
    for (int j = 0; j < 4; ++j)
      bfr[j] = *(const bf16x8*)(Bb + (brow0 + j * 16) * 64 + swz);
#pragma unroll
    for (int i = 0; i < 8; ++i)
      af[i] = *(const bf16x8*)(Ab + (arow0 + i * 16) * 64 + swz);

    // stage tile t+2 into ring slot (its previous occupant t-1 was fully read
    // during iter t-1; the end-of-(t-1) barrier makes that collective).
    if (t < 62) { STAGE_A(sbuf, t + 2) STAGE_B(sbuf, t + 2) }

#pragma unroll
    for (int i = 0; i < 8; ++i)
#pragma unroll
      for (int j = 0; j < 4; ++j)
        acc[i][j] = MFMA16(af[i], bfr[j], acc[i][j]);

    // per-wave: tile t+1's 4 loads landed (t+2's 4 still in flight);
    // barrier makes it collective. ONE barrier per K-iter, never vmcnt(0)
    // in steady state.
    if (t < 62) {
      asm volatile("s_waitcnt vmcnt(4)" ::: "memory");
    } else if (t == 62) {
      asm volatile("s_waitcnt vmcnt(0)" ::: "memory");
    }
    __builtin_amdgcn_s_barrier();
    __builtin_amdgcn_sched_barrier(0);

    c += 1; if (c >= 3) c -= 3;
  }
#undef STAGE_A
#undef STAGE_B
}

// ---------------- QKV projection GEMM (256^2 tile), scatter to tile-major ----------------
__global__ void __launch_bounds__(512, 2) gemm_qkv_kernel(
    const bf16* __restrict__ Xb, const bf16* __restrict__ W0, const bf16* __restrict__ W1,
    const bf16* __restrict__ W2, bf16* __restrict__ q_t, bf16* __restrict__ k_t,
    bf16* __restrict__ v_t) {
  __shared__ char lds[98304];
  int bid = blockIdx.x;
  int xcd = bid & 7, idx = bid >> 3;          // 768 = 8 XCD chunks of 96
  int by = xcd * 4 + idx / 24, bx = idx % 24; // m-major within chunk for L2 reuse
  int which = bx >> 3;
  int m0 = by * 256, n0 = (bx & 7) * 256;
  const bf16* W = which == 0 ? W0 : (which == 1 ? W1 : W2);

  f32x4 acc[8][4] = {};
  gemm256_core(Xb + (size_t)m0 * 2048, W + (size_t)n0 * 2048, lds, acc);

  int lane = threadIdx.x & 63, wid = threadIdx.x >> 6;
  int g = lane >> 4, r16 = lane & 15;
  int wm = wid >> 2, wn = wid & 3;
#pragma unroll
  for (int i = 0; i < 8; ++i) {
#pragma unroll
    for (int r = 0; r < 4; ++r) {
      int m = m0 + wm * 128 + i * 16 + g * 4 + r;
      int b = m >> 12, s = m & 4095;
      int hg = s >> 6, wg = s & 63;
      int t = ((hg >> 3) << 2) + (wg >> 4);
      int tn = ((hg & 7) << 4) + (wg & 15);
#pragma unroll
      for (int j = 0; j < 4; ++j) {
        int n = n0 + wn * 64 + j * 16 + r16;
        int h = n >> 6, hd = n & 63;
        float val = acc[i][j][r];
        size_t base = ((size_t)(b * 32 + h) * 32 + t);
        if (which == 0)
          q_t[(base * 128 + tn) * 64 + hd] = (bf16)(val * 0.125f);
        else if (which == 1)
          k_t[(base * 128 + tn) * 64 + hd] = (bf16)val;
        else
          v_t[(base * 64 + hd) * 128 + tn] = (bf16)val;
      }
    }
  }
}

// ---------------- output GEMM: out = o_bf @ Wo, fp32 row-major ----------------
__global__ void __launch_bounds__(512, 2) gemm_out_kernel(const bf16* __restrict__ A,
                                                          const bf16* __restrict__ W,
                                                          float* __restrict__ C) {
  __shared__ char lds[98304];
  int bid = blockIdx.x;
  int xcd = bid & 7, idx = bid >> 3;         // 256 = 8 chunks of 32
  int by = xcd * 4 + idx / 8, bx = idx & 7;
  int m0 = by * 256, n0 = bx * 256;

  f32x4 acc[8][4] = {};
  gemm256_core(A + (size_t)m0 * 2048, W + (size_t)n0 * 2048, lds, acc);

  int lane = threadIdx.x & 63, wid = threadIdx.x >> 6;
  int g = lane >> 4, r16 = lane & 15;
  int wm = wid >> 2, wn = wid & 3;
#pragma unroll
  for (int i = 0; i < 8; ++i)
#pragma unroll
    for (int j = 0; j < 4; ++j)
#pragma unroll
      for (int r = 0; r < 4; ++r) {
        int m = m0 + wm * 128 + i * 16 + g * 4 + r;
        int n = n0 + wn * 64 + j * 16 + r16;
        C[(size_t)m * 2048 + n] = acc[i][j][r];
      }
}

// ---------------- block-sparse tile attention (unchanged, passing) ----------------
__global__ void __launch_bounds__(256) attn_kernel(const bf16* __restrict__ q_t,
                                                   const bf16* __restrict__ k_t,
                                                   const bf16* __restrict__ v_t,
                                                   bf16* __restrict__ o_bf) {
  __shared__ char Pl[128 * 256];  // P tile, bf16, XOR-swizzled rows of 256B
  int bid = blockIdx.x;
  int t = bid & 31, bh = bid >> 5;
  int h = bh & 31, b = bh >> 5;
  int tid = threadIdx.x, w = tid >> 6, lane = tid & 63;
  int g = lane >> 4, r16 = lane & 15;

  const size_t qoff = (size_t)bid * (128 * 64);
  bf16x8 qf[2][2];
#pragma unroll
  for (int mf = 0; mf < 2; ++mf)
#pragma unroll
    for (int kf = 0; kf < 2; ++kf)
      qf[mf][kf] = *(const bf16x8*)&q_t[qoff + (size_t)(w * 32 + mf * 16 + r16) * 64 + kf * 32 + g * 8];

  f32x4 oacc[2][4] = {};
  float mrun[2][4], lrun[2][4];
#pragma unroll
  for (int mf = 0; mf < 2; ++mf)
#pragma unroll
    for (int r = 0; r < 4; ++r) { mrun[mf][r] = -1e30f; lrun[mf][r] = 0.f; }

  int qh = t >> 2, qw = t & 3;
  int ch = qh < 1 ? 1 : (qh > 7 ? 7 : qh);
  int cw = qw < 1 ? 1 : (qw > 3 ? 3 : qw);

  for (int c = 0; c < 4; ++c) {
    int vt = (ch - 1 + (c >> 1)) * 4 + (cw - 1 + (c & 1));
    const bf16* Kt = k_t + ((size_t)bh * 32 + vt) * (128 * 64);
    const bf16* Vt = v_t + ((size_t)bh * 32 + vt) * (128 * 64);

    f32x4 s[2][8];
#pragma unroll
    for (int nf = 0; nf < 8; ++nf) {
      bf16x8 kf0 = *(const bf16x8*)&Kt[(nf * 16 + r16) * 64 + g * 8];
      bf16x8 kf1 = *(const bf16x8*)&Kt[(nf * 16 + r16) * 64 + 32 + g * 8];
#pragma unroll
      for (int mf = 0; mf < 2; ++mf) {
        f32x4 z = {};
        z = MFMA16(qf[mf][0], kf0, z);
        z = MFMA16(qf[mf][1], kf1, z);
        s[mf][nf] = z;
      }
    }

#pragma unroll
    for (int mf = 0; mf < 2; ++mf) {
#pragma unroll
      for (int r = 0; r < 4; ++r) {
        float mx = s[mf][0][r];
#pragma unroll
        for (int nf = 1; nf < 8; ++nf) mx = fmaxf(mx, s[mf][nf][r]);
        mx = fmaxf(mx, __shfl_xor(mx, 1));
        mx = fmaxf(mx, __shfl_xor(mx, 2));
        mx = fmaxf(mx, __shfl_xor(mx, 4));
        mx = fmaxf(mx, __shfl_xor(mx, 8));
        float mold = mrun[mf][r];
        float mnew = fmaxf(mold, mx);
        float sc = __expf(mold - mnew);
        mrun[mf][r] = mnew;
        float ps = 0.f;
#pragma unroll
        for (int nf = 0; nf < 8; ++nf) {
          float p = __expf(s[mf][nf][r] - mnew);
          s[mf][nf][r] = p;
          ps += p;
        }
        ps += __shfl_xor(ps, 1);
        ps += __shfl_xor(ps, 2);
        ps += __shfl_xor(ps, 4);
        ps += __shfl_xor(ps, 8);
        lrun[mf][r] = lrun[mf][r] * sc + ps;
#pragma unroll
        for (int hf = 0; hf < 4; ++hf) oacc[mf][hf][r] *= sc;
      }
    }

#pragma unroll
    for (int mf = 0; mf < 2; ++mf)
#pragma unroll
      for (int r = 0; r < 4; ++r) {
        int row = w * 32 + mf * 16 + g * 4 + r;
        int rb = row * 256;
        int swzp = (row & 7) << 4;
#pragma unroll
        for (int nf = 0; nf < 8; ++nf) {
          int addr = (rb + (nf * 16 + r16) * 2) ^ swzp;
          *(bf16*)(Pl + addr) = (bf16)s[mf][nf][r];
        }
      }
    __syncthreads();

#pragma unroll
    for (int ks = 0; ks < 4; ++ks) {
      bf16x8 pf[2];
#pragma unroll
      for (int mf = 0; mf < 2; ++mf) {
        int row = w * 32 + mf * 16 + r16;
        int addr = (row * 256 + ks * 64 + g * 16) ^ ((row & 7) << 4);
        pf[mf] = *(const bf16x8*)(Pl + addr);
      }
      bf16x8 vf[4];
#pragma unroll
      for (int hf = 0; hf < 4; ++hf)
        vf[hf] = *(const bf16x8*)&Vt[(hf * 16 + r16) * 128 + ks * 32 + g * 8];
#pragma unroll
      for (int mf = 0; mf < 2; ++mf)
#pragma unroll
        for (int hf = 0; hf < 4; ++hf)
          oacc[mf][hf] = MFMA16(pf[mf], vf[hf], oacc[mf][hf]);
    }
    __syncthreads();
  }

  int nth = t >> 2, ntw = t & 3;
#pragma unroll
  for (int mf = 0; mf < 2; ++mf)
#pragma unroll
    for (int r = 0; r < 4; ++r) {
      float inv = __builtin_amdgcn_rcpf(lrun[mf][r]);
      int tn = w * 32 + mf * 16 + g * 4 + r;
      int stok = (nth * 8 + (tn >> 4)) * 64 + ntw * 16 + (tn & 15);
#pragma unroll
      for (int hf = 0; hf < 4; ++hf) {
        int col = h * 64 + hf * 16 + r16;
        o_bf[((size_t)b * 4096 + stok) * 2048 + col] = (bf16)(oacc[mf][hf][r] * inv);
      }
    }
}

// ---------------- launcher ----------------
extern "C" void kernel_launch(void* const* d_in, const int* in_sizes, int n_in,
                              void* d_out, int out_size, void* d_ws, size_t ws_size,
                              hipStream_t stream) {
  const float* X = (const float*)d_in[0];
  const float* Wq = (const float*)d_in[1];
  const float* Wk = (const float*)d_in[2];
  const float* Wv = (const float*)d_in[3];
  const float* Wo = (const float*)d_in[4];
  float* out = (float*)d_out;
  char* ws = (char*)d_ws;
  if (ws_size < 159383552u) return;  // need ~159.4 MB scratch

  bf16* Xb  = (bf16*)(ws + 0);           // 33.5 MB, later reused as o_bf
  bf16* WT0 = (bf16*)(ws + 33554432u);   // 8.4 MB (WqT, later WoT)
  bf16* WT1 = (bf16*)(ws + 41943040u);   // WkT
  bf16* WT2 = (bf16*)(ws + 50331648u);   // WvT
  bf16* q_t = (bf16*)(ws + 58720256u);   // 33.5 MB
  bf16* k_t = (bf16*)(ws + 92274688u);   // 33.5 MB
  bf16* v_t = (bf16*)(ws + 125829120u);  // 33.5 MB
  bf16* o_bf = Xb;

  cast_x_kernel<<<16384, 256, 0, stream>>>(X, Xb);
  transpose_w_kernel<<<1024, 256, 0, stream>>>(Wq, WT0);
  transpose_w_kernel<<<1024, 256, 0, stream>>>(Wk, WT1);
  transpose_w_kernel<<<1024, 256, 0, stream>>>(Wv, WT2);
  gemm_qkv_kernel<<<768, 512, 0, stream>>>(Xb, WT0, WT1, WT2, q_t, k_t, v_t);
  attn_kernel<<<2048, 256, 0, stream>>>(q_t, k_t, v_t, o_bf);
  transpose_w_kernel<<<1024, 256, 0, stream>>>(Wo, WT0);
  gemm_out_kernel<<<256, 512, 0, stream>>>(o_bf, WT0, out);
}